// Round 1
// baseline (782.862 us; speedup 1.0000x reference)
//
#include <hip/hip_runtime.h>
#include <hip/hip_bf16.h>

#define B_  32
#define S_  4096
#define H_  1024
#define M_  (B_*S_)          // 131072 rows of enc

typedef __attribute__((ext_vector_type(8))) short bf16x8;
typedef __attribute__((ext_vector_type(4))) float f32x4;

typedef void __attribute__((address_space(3)))* lds_ptr_t;
typedef void __attribute__((address_space(1)))* gbl_ptr_t;

__device__ __forceinline__ unsigned short f2bf(float x) {
    return __builtin_bit_cast(unsigned short, __float2bfloat16(x));
}

__device__ __forceinline__ float tanh_fast(float x) {
    // tanh(x) = 1 - 2/(exp(2x)+1); v_exp-based, handles +-inf saturation correctly
    float e = __expf(2.0f * x);
    return 1.0f - 2.0f / (e + 1.0f);
}

// ---------------- Wh fp32 -> bf16 (2 MB, one-time per call) ----------------
__global__ __launch_bounds__(256) void k_cvt_bf16(const float* __restrict__ in,
                                                  unsigned short* __restrict__ out, int n4) {
    int i = blockIdx.x * 256 + threadIdx.x;
    if (i < n4) {
        float4 f = reinterpret_cast<const float4*>(in)[i];
        ushort4 u;
        u.x = f2bf(f.x); u.y = f2bf(f.y); u.z = f2bf(f.z); u.w = f2bf(f.w);
        reinterpret_cast<ushort4*>(out)[i] = u;
    }
}

// ---------------- q_proj[b][o] = sum_k query[b][k] * Ws[o][k] ----------------
__global__ __launch_bounds__(256) void k_qproj(const float* __restrict__ q,
                                               const float* __restrict__ Ws,
                                               float* __restrict__ qp) {
    const int b = blockIdx.y, oc = blockIdx.x, tid = threadIdx.x;
    __shared__ float ql[H_];
    for (int i = tid; i < H_; i += 256) ql[i] = q[b*H_ + i];
    __syncthreads();
    const int o = oc*256 + tid;
    const float4* w = reinterpret_cast<const float4*>(&Ws[(size_t)o * H_]);
    float acc = 0.f;
    #pragma unroll 4
    for (int k4 = 0; k4 < H_/4; ++k4) {
        float4 ww = w[k4];
        acc += ql[k4*4+0]*ww.x + ql[k4*4+1]*ww.y + ql[k4*4+2]*ww.z + ql[k4*4+3]*ww.w;
    }
    qp[b*H_ + o] = acc;
}

// ---------------- fused scores GEMM ----------------
// C-tile = enc(bf16,in-flight) @ Wh_bf16^T, epilogue: v * tanh(qp + x), row-reduce,
// write partial score per (row, n-tile) to sp[bn][row]. No atomics.
__global__ __launch_bounds__(256) void k_scores(const float* __restrict__ enc,
                                                const unsigned short* __restrict__ whb,
                                                const float* __restrict__ qp,
                                                const float* __restrict__ vw,
                                                float* __restrict__ sp) {
    __shared__ __align__(16) unsigned short As[2][128][32];   // 16 KB
    __shared__ __align__(16) unsigned short Bs[2][128][32];   // 16 KB
    __shared__ float sred[2][128];                            // 1 KB

    const int tid  = threadIdx.x;
    const int lane = tid & 63;
    const int wid  = tid >> 6;
    const int wr = wid >> 1, wc = wid & 1;
    const int fr = lane & 15;            // fragment row/col (A-row / B-col)
    const int fk = (lane >> 4) * 8;      // fragment k offset

    const int bn = blockIdx.x;           // 0..7   (N tiles)
    const int bm = blockIdx.y;           // 0..1023 (M tiles)
    const int row0 = bm * 128;
    const int col0 = bn * 128;
    const int b = row0 >> 12;            // 4096 rows per batch, tiles never straddle b

    // A staging map: pass p, row = p*32 + (tid>>3), k-offset = (tid&7)*4 (one float4)
    const int ar = tid >> 3;
    const int ak = (tid & 7) * 4;
    // B staging map (global_load_lds, 16B): instr i covers n = i*64 + (tid>>2), kk=(tid&3)*8
    const int bnr = tid >> 2;
    const int bkk = (tid & 3) * 8;

    float4 areg[4];

    auto loadA = [&](int kt) {
        #pragma unroll
        for (int p = 0; p < 4; ++p)
            areg[p] = *reinterpret_cast<const float4*>(
                &enc[(size_t)(row0 + p*32 + ar) * H_ + kt*32 + ak]);
    };
    auto writeA = [&](int buf) {
        #pragma unroll
        for (int p = 0; p < 4; ++p) {
            ushort4 u;
            u.x = f2bf(areg[p].x); u.y = f2bf(areg[p].y);
            u.z = f2bf(areg[p].z); u.w = f2bf(areg[p].w);
            *reinterpret_cast<ushort4*>(&As[buf][p*32 + ar][ak]) = u;
        }
    };
    auto stageB = [&](int buf, int kt) {
        const unsigned short* g0 = whb + (size_t)(col0 + bnr) * H_ + kt*32 + bkk;
        const unsigned short* g1 = g0 + (size_t)64 * H_;
        char* l0 = (char*)(&Bs[buf][0][0]) + tid*16;
        __builtin_amdgcn_global_load_lds((gbl_ptr_t)g0, (lds_ptr_t)l0,        16, 0, 0);
        __builtin_amdgcn_global_load_lds((gbl_ptr_t)g1, (lds_ptr_t)(l0+4096), 16, 0, 0);
    };

    f32x4 acc[4][4] = {};

    loadA(0);
    stageB(0, 0);
    writeA(0);
    __syncthreads();

    for (int kt = 0; kt < 32; ++kt) {
        const int cur = kt & 1, nxt = cur ^ 1;
        if (kt < 31) { stageB(nxt, kt + 1); loadA(kt + 1); }

        bf16x8 af[4], bfr[4];
        #pragma unroll
        for (int i = 0; i < 4; ++i) {
            af[i]  = *reinterpret_cast<const bf16x8*>(&As[cur][wr*64 + i*16 + fr][fk]);
            bfr[i] = *reinterpret_cast<const bf16x8*>(&Bs[cur][wc*64 + i*16 + fr][fk]);
        }
        #pragma unroll
        for (int i = 0; i < 4; ++i)
            #pragma unroll
            for (int j = 0; j < 4; ++j)
                acc[i][j] = __builtin_amdgcn_mfma_f32_16x16x32_bf16(af[i], bfr[j], acc[i][j], 0, 0, 0);

        if (kt < 31) writeA(nxt);
        __syncthreads();
    }

    // epilogue: s_partial[row] = sum_c v[c] * tanh(qp[b][c] + x[row][c])
    float vv[4], qq[4];
    #pragma unroll
    for (int j = 0; j < 4; ++j) {
        int c = col0 + wc*64 + j*16 + fr;
        vv[j] = vw[c];
        qq[j] = qp[b*H_ + c];
    }
    #pragma unroll
    for (int i = 0; i < 4; ++i) {
        #pragma unroll
        for (int r = 0; r < 4; ++r) {
            float s = 0.f;
            #pragma unroll
            for (int j = 0; j < 4; ++j)
                s += vv[j] * tanh_fast(qq[j] + acc[i][j][r]);
            #pragma unroll
            for (int m = 1; m < 16; m <<= 1)
                s += __shfl_xor(s, m, 64);
            if (fr == 0)
                sred[wc][wr*64 + i*16 + (lane >> 4)*4 + r] = s;
        }
    }
    __syncthreads();
    if (tid < 128)
        sp[(size_t)bn * M_ + row0 + tid] = sred[0][tid] + sred[1][tid];
}

// ---------------- softmax over S per batch ----------------
__global__ __launch_bounds__(256) void k_softmax(const float* __restrict__ sp,
                                                 float* __restrict__ attn) {
    const int b = blockIdx.x, tid = threadIdx.x;
    __shared__ float red[4];
    float vals[16];
    float mx = -1e30f;
    #pragma unroll
    for (int i = 0; i < 16; ++i) {
        int s = i*256 + tid;
        float x = 0.f;
        #pragma unroll
        for (int p = 0; p < 8; ++p) x += sp[(size_t)p*M_ + b*S_ + s];
        vals[i] = x;
        mx = fmaxf(mx, x);
    }
    #pragma unroll
    for (int m = 1; m < 64; m <<= 1) mx = fmaxf(mx, __shfl_xor(mx, m, 64));
    if ((tid & 63) == 0) red[tid >> 6] = mx;
    __syncthreads();
    mx = fmaxf(fmaxf(red[0], red[1]), fmaxf(red[2], red[3]));
    float sum = 0.f;
    #pragma unroll
    for (int i = 0; i < 16; ++i) { vals[i] = __expf(vals[i] - mx); sum += vals[i]; }
    #pragma unroll
    for (int m = 1; m < 64; m <<= 1) sum += __shfl_xor(sum, m, 64);
    __syncthreads();
    if ((tid & 63) == 0) red[tid >> 6] = sum;
    __syncthreads();
    sum = red[0] + red[1] + red[2] + red[3];
    float inv = 1.f / sum;
    #pragma unroll
    for (int i = 0; i < 16; ++i) attn[b*S_ + i*256 + tid] = vals[i] * inv;
}

// ---------------- ctx partials: ctxp[sc][b][h] = sum_{s in chunk} attn*enc ----------------
__global__ __launch_bounds__(256) void k_ctx(const float* __restrict__ attn,
                                             const float* __restrict__ enc,
                                             float* __restrict__ ctxp) {
    const int sc = blockIdx.x;      // 0..15
    const int b  = blockIdx.y;
    const int h  = threadIdx.x * 4;
    float ax = 0.f, ay = 0.f, az = 0.f, aw = 0.f;
    const int s0 = sc * 256;
    #pragma unroll 4
    for (int s = s0; s < s0 + 256; ++s) {
        float a = attn[b*S_ + s];
        float4 e = *reinterpret_cast<const float4*>(&enc[((size_t)b*S_ + s) * H_ + h]);
        ax += a*e.x; ay += a*e.y; az += a*e.z; aw += a*e.w;
    }
    float4 o; o.x = ax; o.y = ay; o.z = az; o.w = aw;
    *reinterpret_cast<float4*>(&ctxp[((size_t)sc*B_ + b) * H_ + h]) = o;
}

// ---------------- out[b][o] = tanh(sum_k cat[b][k] * Wout[o][k]) ----------------
__global__ __launch_bounds__(256) void k_out(const float* __restrict__ ctxp,
                                             const float* __restrict__ q,
                                             const float* __restrict__ Wout,
                                             float* __restrict__ out) {
    const int oc = blockIdx.x, b = blockIdx.y, tid = threadIdx.x;
    __shared__ float cat[2*H_];
    for (int k = tid; k < H_; k += 256) {
        float s = 0.f;
        #pragma unroll
        for (int p = 0; p < 16; ++p) s += ctxp[((size_t)p*B_ + b) * H_ + k];
        cat[k] = s;
        cat[H_ + k] = q[b*H_ + k];
    }
    __syncthreads();
    const int o = oc*256 + tid;
    const float4* w = reinterpret_cast<const float4*>(&Wout[(size_t)o * 2*H_]);
    float acc = 0.f;
    #pragma unroll 4
    for (int k4 = 0; k4 < 2*H_/4; ++k4) {
        float4 ww = w[k4];
        acc += cat[k4*4+0]*ww.x + cat[k4*4+1]*ww.y + cat[k4*4+2]*ww.z + cat[k4*4+3]*ww.w;
    }
    out[b*H_ + o] = tanh_fast(acc);
}

extern "C" void kernel_launch(void* const* d_in, const int* in_sizes, int n_in,
                              void* d_out, int out_size, void* d_ws, size_t ws_size,
                              hipStream_t stream) {
    const float* query = (const float*)d_in[0];
    const float* enc   = (const float*)d_in[1];
    // d_in[2] = src_lengths (int64) — dead in the reference, faithfully unused
    const float* Ws    = (const float*)d_in[3];
    const float* Wh    = (const float*)d_in[4];
    const float* vw    = (const float*)d_in[5];
    const float* Wout  = (const float*)d_in[6];
    float* out = (float*)d_out;

    char* ws = (char*)d_ws;
    unsigned short* whb = (unsigned short*)ws;                 // [1024][1024] bf16, 2 MB
    float* sp   = (float*)(ws + (2u  << 20));                  // [8][131072]  4 MB
    float* attn = (float*)(ws + (6u  << 20));                  // [32][4096]   512 KB
    float* qp   = (float*)(ws + (6u  << 20) + (512u << 10));   // [32][1024]   128 KB
    float* ctxp = (float*)(ws + (7u  << 20));                  // [16][32][1024] 2 MB
    // total ws footprint: 9 MB; every buffer fully written before read each call

    k_cvt_bf16<<<dim3(1024),   dim3(256), 0, stream>>>(Wh, whb, H_*H_/4);
    k_qproj   <<<dim3(4, 32),  dim3(256), 0, stream>>>(query, Ws, qp);
    k_scores  <<<dim3(8, 1024),dim3(256), 0, stream>>>(enc, whb, qp, vw, sp);
    k_softmax <<<dim3(32),     dim3(256), 0, stream>>>(sp, attn);
    k_ctx     <<<dim3(16, 32), dim3(256), 0, stream>>>(attn, enc, ctxp);
    k_out     <<<dim3(4, 32),  dim3(256), 0, stream>>>(ctxp, query, Wout, out);
}

// Round 2
// 672.041 us; speedup vs baseline: 1.1649x; 1.1649x over previous
//
#include <hip/hip_runtime.h>
#include <hip/hip_bf16.h>

#define B_  32
#define S_  4096
#define H_  1024
#define M_  (B_*S_)          // 131072 rows of enc

typedef __attribute__((ext_vector_type(8))) short bf16x8;
typedef __attribute__((ext_vector_type(4))) float f32x4;
typedef __attribute__((ext_vector_type(8))) unsigned short ushort8;

typedef void __attribute__((address_space(3)))* lds_ptr_t;
typedef void __attribute__((address_space(1)))* gbl_ptr_t;

__device__ __forceinline__ unsigned short f2bf(float x) {
    return __builtin_bit_cast(unsigned short, __float2bfloat16(x));
}
__device__ __forceinline__ float bf2f(unsigned short u) {
    return __builtin_bit_cast(float, (unsigned)u << 16);
}
__device__ __forceinline__ float tanh_fast(float x) {
    float e = __expf(2.0f * x);
    return 1.0f - 2.0f / (e + 1.0f);
}

// ---------------- fp32 -> bf16 converters ----------------
__global__ __launch_bounds__(256) void k_cvt_bf16(const float* __restrict__ in,
                                                  unsigned short* __restrict__ out, int n4) {
    int i = blockIdx.x * 256 + threadIdx.x;
    if (i < n4) {
        float4 f = reinterpret_cast<const float4*>(in)[i];
        ushort4 u;
        u.x = f2bf(f.x); u.y = f2bf(f.y); u.z = f2bf(f.z); u.w = f2bf(f.w);
        reinterpret_cast<ushort4*>(out)[i] = u;
    }
}

__global__ __launch_bounds__(256) void k_cvt_enc(const float* __restrict__ in,
                                                 unsigned short* __restrict__ out, int n8) {
    const int stride = gridDim.x * 256;
    for (int i = blockIdx.x * 256 + threadIdx.x; i < n8; i += stride) {
        float4 a = reinterpret_cast<const float4*>(in)[(size_t)i * 2];
        float4 b = reinterpret_cast<const float4*>(in)[(size_t)i * 2 + 1];
        ushort8 u;
        u[0] = f2bf(a.x); u[1] = f2bf(a.y); u[2] = f2bf(a.z); u[3] = f2bf(a.w);
        u[4] = f2bf(b.x); u[5] = f2bf(b.y); u[6] = f2bf(b.z); u[7] = f2bf(b.w);
        reinterpret_cast<ushort8*>(out)[i] = u;
    }
}

// ---------------- q_proj[b][o] = sum_k query[b][k] * Ws[o][k] ----------------
__global__ __launch_bounds__(256) void k_qproj(const float* __restrict__ q,
                                               const float* __restrict__ Ws,
                                               float* __restrict__ qp) {
    const int b = blockIdx.y, oc = blockIdx.x, tid = threadIdx.x;
    __shared__ float ql[H_];
    for (int i = tid; i < H_; i += 256) ql[i] = q[b*H_ + i];
    __syncthreads();
    const int o = oc*256 + tid;
    const float4* w = reinterpret_cast<const float4*>(&Ws[(size_t)o * H_]);
    float acc = 0.f;
    #pragma unroll 4
    for (int k4 = 0; k4 < H_/4; ++k4) {
        float4 ww = w[k4];
        acc += ql[k4*4+0]*ww.x + ql[k4*4+1]*ww.y + ql[k4*4+2]*ww.z + ql[k4*4+3]*ww.w;
    }
    qp[b*H_ + o] = acc;
}

// ---------------- fused scores GEMM, bf16 A (m97 structure) ----------------
// C-tile(128x128) = encb @ whb^T ; epilogue v*tanh(qp+x) row-reduce -> sp[bn][row]
__global__ __launch_bounds__(256) void k_scores_b(const unsigned short* __restrict__ encb,
                                                  const unsigned short* __restrict__ whb,
                                                  const float* __restrict__ qp,
                                                  const float* __restrict__ vw,
                                                  float* __restrict__ sp) {
    __shared__ __align__(16) unsigned short As[2][128][32];   // 8 KB x2
    __shared__ __align__(16) unsigned short Bs[2][128][32];   // 8 KB x2
    __shared__ float sred[2][128];

    const int tid  = threadIdx.x;
    const int lane = tid & 63;
    const int wid  = tid >> 6;
    const int wr = wid >> 1, wc = wid & 1;
    const int fr = lane & 15;
    const int fk = (lane >> 4) * 8;

    // XCD-group swizzle: 8 bn-tiles of one bm land on the same XCD back-to-back
    const int h  = blockIdx.x;                 // 8192 blocks, 8192 % 8 == 0
    const int L  = (h & 7) * 1024 + (h >> 3);  // bijective
    const int bm = L >> 3;
    const int bn = L & 7;
    const int row0 = bm * 128;
    const int col0 = bn * 128;
    const int b = row0 >> 12;

    // staging map: instr covers 4096 B = 64 rows; thread t -> row t>>2, k = (t&3)*8
    const int sr = tid >> 2;
    const int sk = (tid & 3) * 8;

    auto stage = [&](int buf, int kt) {
        const unsigned short* ga0 = encb + (size_t)(row0 + sr) * H_ + kt*32 + sk;
        const unsigned short* gb0 = whb  + (size_t)(col0 + sr) * H_ + kt*32 + sk;
        char* la = (char*)(&As[buf][0][0]) + tid*16;
        char* lb = (char*)(&Bs[buf][0][0]) + tid*16;
        __builtin_amdgcn_global_load_lds((gbl_ptr_t)ga0,                 (lds_ptr_t)la,        16, 0, 0);
        __builtin_amdgcn_global_load_lds((gbl_ptr_t)(ga0 + (size_t)64*H_),(lds_ptr_t)(la+4096), 16, 0, 0);
        __builtin_amdgcn_global_load_lds((gbl_ptr_t)gb0,                 (lds_ptr_t)lb,        16, 0, 0);
        __builtin_amdgcn_global_load_lds((gbl_ptr_t)(gb0 + (size_t)64*H_),(lds_ptr_t)(lb+4096), 16, 0, 0);
    };

    f32x4 acc[4][4] = {};

    stage(0, 0);
    __syncthreads();

    for (int kt = 0; kt < 32; ++kt) {
        const int cur = kt & 1, nxt = cur ^ 1;
        if (kt < 31) stage(nxt, kt + 1);

        bf16x8 af[4], bfr[4];
        #pragma unroll
        for (int i = 0; i < 4; ++i) {
            af[i]  = *reinterpret_cast<const bf16x8*>(&As[cur][wr*64 + i*16 + fr][fk]);
            bfr[i] = *reinterpret_cast<const bf16x8*>(&Bs[cur][wc*64 + i*16 + fr][fk]);
        }
        #pragma unroll
        for (int i = 0; i < 4; ++i)
            #pragma unroll
            for (int j = 0; j < 4; ++j)
                acc[i][j] = __builtin_amdgcn_mfma_f32_16x16x32_bf16(af[i], bfr[j], acc[i][j], 0, 0, 0);

        __syncthreads();
    }

    // epilogue: s_partial[row] = sum_c v[c] * tanh(qp[b][c] + x[row][c])
    float vv[4], qq[4];
    #pragma unroll
    for (int j = 0; j < 4; ++j) {
        int c = col0 + wc*64 + j*16 + fr;
        vv[j] = vw[c];
        qq[j] = qp[b*H_ + c];
    }
    #pragma unroll
    for (int i = 0; i < 4; ++i) {
        #pragma unroll
        for (int r = 0; r < 4; ++r) {
            float s = 0.f;
            #pragma unroll
            for (int j = 0; j < 4; ++j)
                s += vv[j] * tanh_fast(qq[j] + acc[i][j][r]);
            #pragma unroll
            for (int m = 1; m < 16; m <<= 1)
                s += __shfl_xor(s, m, 64);
            if (fr == 0)
                sred[wc][wr*64 + i*16 + (lane >> 4)*4 + r] = s;
        }
    }
    __syncthreads();
    if (tid < 128)
        sp[(size_t)bn * M_ + row0 + tid] = sred[0][tid] + sred[1][tid];
}

// ---------------- fused scores GEMM, fp32 A in-flight (fallback) ----------------
__global__ __launch_bounds__(256) void k_scores_f(const float* __restrict__ enc,
                                                  const unsigned short* __restrict__ whb,
                                                  const float* __restrict__ qp,
                                                  const float* __restrict__ vw,
                                                  float* __restrict__ sp) {
    __shared__ __align__(16) unsigned short As[2][128][32];
    __shared__ __align__(16) unsigned short Bs[2][128][32];
    __shared__ float sred[2][128];

    const int tid  = threadIdx.x;
    const int lane = tid & 63;
    const int wid  = tid >> 6;
    const int wr = wid >> 1, wc = wid & 1;
    const int fr = lane & 15;
    const int fk = (lane >> 4) * 8;

    const int h  = blockIdx.x;
    const int L  = (h & 7) * 1024 + (h >> 3);
    const int bm = L >> 3;
    const int bn = L & 7;
    const int row0 = bm * 128;
    const int col0 = bn * 128;
    const int b = row0 >> 12;

    const int ar = tid >> 3;
    const int ak = (tid & 7) * 4;
    const int bnr = tid >> 2;
    const int bkk = (tid & 3) * 8;

    float4 areg[4];
    auto loadA = [&](int kt) {
        #pragma unroll
        for (int p = 0; p < 4; ++p)
            areg[p] = *reinterpret_cast<const float4*>(
                &enc[(size_t)(row0 + p*32 + ar) * H_ + kt*32 + ak]);
    };
    auto writeA = [&](int buf) {
        #pragma unroll
        for (int p = 0; p < 4; ++p) {
            ushort4 u;
            u.x = f2bf(areg[p].x); u.y = f2bf(areg[p].y);
            u.z = f2bf(areg[p].z); u.w = f2bf(areg[p].w);
            *reinterpret_cast<ushort4*>(&As[buf][p*32 + ar][ak]) = u;
        }
    };
    auto stageB = [&](int buf, int kt) {
        const unsigned short* g0 = whb + (size_t)(col0 + bnr) * H_ + kt*32 + bkk;
        const unsigned short* g1 = g0 + (size_t)64 * H_;
        char* l0 = (char*)(&Bs[buf][0][0]) + tid*16;
        __builtin_amdgcn_global_load_lds((gbl_ptr_t)g0, (lds_ptr_t)l0,        16, 0, 0);
        __builtin_amdgcn_global_load_lds((gbl_ptr_t)g1, (lds_ptr_t)(l0+4096), 16, 0, 0);
    };

    f32x4 acc[4][4] = {};

    loadA(0);
    stageB(0, 0);
    writeA(0);
    __syncthreads();

    for (int kt = 0; kt < 32; ++kt) {
        const int cur = kt & 1, nxt = cur ^ 1;
        if (kt < 31) { stageB(nxt, kt + 1); loadA(kt + 1); }

        bf16x8 af[4], bfr[4];
        #pragma unroll
        for (int i = 0; i < 4; ++i) {
            af[i]  = *reinterpret_cast<const bf16x8*>(&As[cur][wr*64 + i*16 + fr][fk]);
            bfr[i] = *reinterpret_cast<const bf16x8*>(&Bs[cur][wc*64 + i*16 + fr][fk]);
        }
        #pragma unroll
        for (int i = 0; i < 4; ++i)
            #pragma unroll
            for (int j = 0; j < 4; ++j)
                acc[i][j] = __builtin_amdgcn_mfma_f32_16x16x32_bf16(af[i], bfr[j], acc[i][j], 0, 0, 0);

        if (kt < 31) writeA(nxt);
        __syncthreads();
    }

    float vv[4], qq[4];
    #pragma unroll
    for (int j = 0; j < 4; ++j) {
        int c = col0 + wc*64 + j*16 + fr;
        vv[j] = vw[c];
        qq[j] = qp[b*H_ + c];
    }
    #pragma unroll
    for (int i = 0; i < 4; ++i) {
        #pragma unroll
        for (int r = 0; r < 4; ++r) {
            float s = 0.f;
            #pragma unroll
            for (int j = 0; j < 4; ++j)
                s += vv[j] * tanh_fast(qq[j] + acc[i][j][r]);
            #pragma unroll
            for (int m = 1; m < 16; m <<= 1)
                s += __shfl_xor(s, m, 64);
            if (fr == 0)
                sred[wc][wr*64 + i*16 + (lane >> 4)*4 + r] = s;
        }
    }
    __syncthreads();
    if (tid < 128)
        sp[(size_t)bn * M_ + row0 + tid] = sred[0][tid] + sred[1][tid];
}

// ---------------- softmax over S per batch ----------------
__global__ __launch_bounds__(256) void k_softmax(const float* __restrict__ sp,
                                                 float* __restrict__ attn) {
    const int b = blockIdx.x, tid = threadIdx.x;
    __shared__ float red[4];
    float vals[16];
    float mx = -1e30f;
    #pragma unroll
    for (int i = 0; i < 16; ++i) {
        int s = i*256 + tid;
        float x = 0.f;
        #pragma unroll
        for (int p = 0; p < 8; ++p) x += sp[(size_t)p*M_ + b*S_ + s];
        vals[i] = x;
        mx = fmaxf(mx, x);
    }
    #pragma unroll
    for (int m = 1; m < 64; m <<= 1) mx = fmaxf(mx, __shfl_xor(mx, m, 64));
    if ((tid & 63) == 0) red[tid >> 6] = mx;
    __syncthreads();
    mx = fmaxf(fmaxf(red[0], red[1]), fmaxf(red[2], red[3]));
    float sum = 0.f;
    #pragma unroll
    for (int i = 0; i < 16; ++i) { vals[i] = __expf(vals[i] - mx); sum += vals[i]; }
    #pragma unroll
    for (int m = 1; m < 64; m <<= 1) sum += __shfl_xor(sum, m, 64);
    __syncthreads();
    if ((tid & 63) == 0) red[tid >> 6] = sum;
    __syncthreads();
    sum = red[0] + red[1] + red[2] + red[3];
    float inv = 1.f / sum;
    #pragma unroll
    for (int i = 0; i < 16; ++i) attn[b*S_ + i*256 + tid] = vals[i] * inv;
}

// ---------------- ctx partials, bf16 enc ----------------
__global__ __launch_bounds__(256) void k_ctx_b(const float* __restrict__ attn,
                                               const unsigned short* __restrict__ encb,
                                               float* __restrict__ ctxp) {
    const int sc = blockIdx.x;      // 0..15
    const int b  = blockIdx.y;
    const int hh = threadIdx.x * 4;
    float ax = 0.f, ay = 0.f, az = 0.f, aw = 0.f;
    const int s0 = sc * 256;
    #pragma unroll 4
    for (int s = s0; s < s0 + 256; ++s) {
        float a = attn[b*S_ + s];
        ushort4 e = *reinterpret_cast<const ushort4*>(&encb[((size_t)b*S_ + s) * H_ + hh]);
        ax += a*bf2f(e.x); ay += a*bf2f(e.y); az += a*bf2f(e.z); aw += a*bf2f(e.w);
    }
    float4 o; o.x = ax; o.y = ay; o.z = az; o.w = aw;
    *reinterpret_cast<float4*>(&ctxp[((size_t)sc*B_ + b) * H_ + hh]) = o;
}

// ---------------- ctx partials, fp32 enc (fallback) ----------------
__global__ __launch_bounds__(256) void k_ctx_f(const float* __restrict__ attn,
                                               const float* __restrict__ enc,
                                               float* __restrict__ ctxp) {
    const int sc = blockIdx.x;
    const int b  = blockIdx.y;
    const int hh = threadIdx.x * 4;
    float ax = 0.f, ay = 0.f, az = 0.f, aw = 0.f;
    const int s0 = sc * 256;
    #pragma unroll 4
    for (int s = s0; s < s0 + 256; ++s) {
        float a = attn[b*S_ + s];
        float4 e = *reinterpret_cast<const float4*>(&enc[((size_t)b*S_ + s) * H_ + hh]);
        ax += a*e.x; ay += a*e.y; az += a*e.z; aw += a*e.w;
    }
    float4 o; o.x = ax; o.y = ay; o.z = az; o.w = aw;
    *reinterpret_cast<float4*>(&ctxp[((size_t)sc*B_ + b) * H_ + hh]) = o;
}

// ---------------- out[b][o] = tanh(sum_k cat[b][k] * Wout[o][k]) ----------------
__global__ __launch_bounds__(256) void k_out(const float* __restrict__ ctxp,
                                             const float* __restrict__ q,
                                             const float* __restrict__ Wout,
                                             float* __restrict__ out) {
    const int oc = blockIdx.x, b = blockIdx.y, tid = threadIdx.x;
    __shared__ float cat[2*H_];
    for (int k = tid; k < H_; k += 256) {
        float s = 0.f;
        #pragma unroll
        for (int p = 0; p < 16; ++p) s += ctxp[((size_t)p*B_ + b) * H_ + k];
        cat[k] = s;
        cat[H_ + k] = q[b*H_ + k];
    }
    __syncthreads();
    const int o = oc*256 + tid;
    const float4* w = reinterpret_cast<const float4*>(&Wout[(size_t)o * 2*H_]);
    float acc = 0.f;
    #pragma unroll 4
    for (int k4 = 0; k4 < 2*H_/4; ++k4) {
        float4 ww = w[k4];
        acc += cat[k4*4+0]*ww.x + cat[k4*4+1]*ww.y + cat[k4*4+2]*ww.z + cat[k4*4+3]*ww.w;
    }
    out[b*H_ + o] = tanh_fast(acc);
}

extern "C" void kernel_launch(void* const* d_in, const int* in_sizes, int n_in,
                              void* d_out, int out_size, void* d_ws, size_t ws_size,
                              hipStream_t stream) {
    const float* query = (const float*)d_in[0];
    const float* enc   = (const float*)d_in[1];
    // d_in[2] = src_lengths (int64) — dead in the reference, faithfully unused
    const float* Ws    = (const float*)d_in[3];
    const float* Wh    = (const float*)d_in[4];
    const float* vw    = (const float*)d_in[5];
    const float* Wout  = (const float*)d_in[6];
    float* out = (float*)d_out;

    char* ws = (char*)d_ws;

    if (ws_size >= (266ull << 20)) {
        // big path: encb (256 MiB) + whb (2) + sp (4) + attn/qp (1) + ctxp (2)
        unsigned short* encb = (unsigned short*)ws;                        // 256 MiB
        unsigned short* whb  = (unsigned short*)(ws + (256ull << 20));     // 2 MiB
        float* sp   = (float*)(ws + (258ull << 20));                       // 4 MiB
        float* attn = (float*)(ws + (262ull << 20));                       // 512 KiB
        float* qp   = (float*)(ws + (262ull << 20) + (512u << 10));        // 128 KiB
        float* ctxp = (float*)(ws + (263ull << 20));                       // 2 MiB

        k_cvt_enc <<<dim3(2048),    dim3(256), 0, stream>>>(enc, encb, M_*H_/8);
        k_cvt_bf16<<<dim3(1024),    dim3(256), 0, stream>>>(Wh, whb, H_*H_/4);
        k_qproj   <<<dim3(4, 32),   dim3(256), 0, stream>>>(query, Ws, qp);
        k_scores_b<<<dim3(8192),    dim3(256), 0, stream>>>(encb, whb, qp, vw, sp);
        k_softmax <<<dim3(32),      dim3(256), 0, stream>>>(sp, attn);
        k_ctx_b   <<<dim3(16, 32),  dim3(256), 0, stream>>>(attn, encb, ctxp);
        k_out     <<<dim3(4, 32),   dim3(256), 0, stream>>>(ctxp, query, Wout, out);
    } else {
        // fallback: round-1 layout (9 MiB)
        unsigned short* whb = (unsigned short*)ws;
        float* sp   = (float*)(ws + (2u  << 20));
        float* attn = (float*)(ws + (6u  << 20));
        float* qp   = (float*)(ws + (6u  << 20) + (512u << 10));
        float* ctxp = (float*)(ws + (7u  << 20));

        k_cvt_bf16<<<dim3(1024),    dim3(256), 0, stream>>>(Wh, whb, H_*H_/4);
        k_qproj   <<<dim3(4, 32),   dim3(256), 0, stream>>>(query, Ws, qp);
        k_scores_f<<<dim3(8192),    dim3(256), 0, stream>>>(enc, whb, qp, vw, sp);
        k_softmax <<<dim3(32),      dim3(256), 0, stream>>>(sp, attn);
        k_ctx_f   <<<dim3(16, 32),  dim3(256), 0, stream>>>(attn, enc, ctxp);
        k_out     <<<dim3(4, 32),   dim3(256), 0, stream>>>(ctxp, query, Wout, out);
    }
}

// Round 3
// 650.867 us; speedup vs baseline: 1.2028x; 1.0325x over previous
//
#include <hip/hip_runtime.h>
#include <hip/hip_bf16.h>

#define B_  32
#define S_  4096
#define H_  1024
#define M_  (B_*S_)          // 131072 rows of enc

typedef __attribute__((ext_vector_type(8))) short bf16x8;
typedef __attribute__((ext_vector_type(4))) float f32x4;
typedef __attribute__((ext_vector_type(8))) unsigned short ushort8;

typedef void __attribute__((address_space(3)))* lds_ptr_t;
typedef void __attribute__((address_space(1)))* gbl_ptr_t;

__device__ __forceinline__ unsigned short f2bf(float x) {
    return __builtin_bit_cast(unsigned short, __float2bfloat16(x));
}
__device__ __forceinline__ float bf2f(unsigned short u) {
    return __builtin_bit_cast(float, (unsigned)u << 16);
}
__device__ __forceinline__ float tanh_fast(float x) {
    float e = __expf(2.0f * x);
    return 1.0f - 2.0f / (e + 1.0f);
}

// ---------------- fp32 -> bf16 converters ----------------
__global__ __launch_bounds__(256) void k_cvt_bf16(const float* __restrict__ in,
                                                  unsigned short* __restrict__ out, int n4) {
    int i = blockIdx.x * 256 + threadIdx.x;
    if (i < n4) {
        float4 f = reinterpret_cast<const float4*>(in)[i];
        ushort4 u;
        u.x = f2bf(f.x); u.y = f2bf(f.y); u.z = f2bf(f.z); u.w = f2bf(f.w);
        reinterpret_cast<ushort4*>(out)[i] = u;
    }
}

__global__ __launch_bounds__(256) void k_cvt_enc(const float* __restrict__ in,
                                                 unsigned short* __restrict__ out, int n8) {
    const int stride = gridDim.x * 256;
    for (int i = blockIdx.x * 256 + threadIdx.x; i < n8; i += stride) {
        float4 a = reinterpret_cast<const float4*>(in)[(size_t)i * 2];
        float4 b = reinterpret_cast<const float4*>(in)[(size_t)i * 2 + 1];
        ushort8 u;
        u[0] = f2bf(a.x); u[1] = f2bf(a.y); u[2] = f2bf(a.z); u[3] = f2bf(a.w);
        u[4] = f2bf(b.x); u[5] = f2bf(b.y); u[6] = f2bf(b.z); u[7] = f2bf(b.w);
        reinterpret_cast<ushort8*>(out)[i] = u;
    }
}

// ---------------- q_proj[b][o] = sum_k query[b][k] * Ws[o][k] ----------------
__global__ __launch_bounds__(256) void k_qproj(const float* __restrict__ q,
                                               const float* __restrict__ Ws,
                                               float* __restrict__ qp) {
    const int b = blockIdx.y, oc = blockIdx.x, tid = threadIdx.x;
    __shared__ float ql[H_];
    for (int i = tid; i < H_; i += 256) ql[i] = q[b*H_ + i];
    __syncthreads();
    const int o = oc*256 + tid;
    const float4* w = reinterpret_cast<const float4*>(&Ws[(size_t)o * H_]);
    float acc = 0.f;
    #pragma unroll 4
    for (int k4 = 0; k4 < H_/4; ++k4) {
        float4 ww = w[k4];
        acc += ql[k4*4+0]*ww.x + ql[k4*4+1]*ww.y + ql[k4*4+2]*ww.z + ql[k4*4+3]*ww.w;
    }
    qp[b*H_ + o] = acc;
}

// ---------------- fused scores GEMM: 256x256 tile, 8-phase, counted vmcnt ----------------
// C(256x256) = encb(row-panel) @ whb^T(col-panel); K=1024 in 16 K-tiles of 64.
// LDS: 2 bufs x (A 32KB + B 32KB) = 128KB, organized as 1024B subtiles [16 rows][32 k] bf16
// so every MFMA fragment ds_read_b128 is a contiguous 1024B per wave (conflict-free).
// Phases per K-tile = C-quadrants (mq,nq), 16 MFMA each, setprio-wrapped, raw barriers,
// one half-tile (2 global_load_lds) staged per phase, vmcnt(6) once per K-tile.
__global__ __launch_bounds__(512, 2) void k_scores8(const unsigned short* __restrict__ encb,
                                                    const unsigned short* __restrict__ whb,
                                                    const float* __restrict__ qp,
                                                    const float* __restrict__ vw,
                                                    float* __restrict__ sp) {
    __shared__ __align__(1024) char smem[131072];

    const int tid = threadIdx.x;
    const int l   = tid & 63;
    const int w   = tid >> 6;      // wave 0..7
    const int wr  = w >> 2;        // 0..1  (row half of the tile)
    const int wc  = w & 3;         // 0..3  (col quarter)
    const int fr  = l & 15;
    const int fh  = l >> 4;

    // XCD-group swizzle: 4 bn tiles of one bm adjacent on the same XCD
    const int hb = blockIdx.x;                // 2048 blocks, 2048 % 8 == 0
    const int L  = (hb & 7) * 256 + (hb >> 3);
    const int bm = L >> 2;
    const int bn = L & 3;
    const int row0 = bm * 256;
    const int col0 = bn * 256;
    const int b = row0 >> 12;      // 4096 rows per batch; 256 | 4096

    const int srow = l >> 2;       // staging: row within subtile
    const int scol = (l & 3) * 8;  // staging: bf16 col within 32

    // ---- staging: one half-tile = 16 subtiles = 2 instructions (8KB each) ----
    auto stageA = [&](int t, int mh) {   // region mh: rblk in {mh*4..+3, 8+mh*4..+3}
        #pragma unroll
        for (int j = 0; j < 2; ++j) {
            int s_local = j*8 + w;
            int g  = s_local >> 1;
            int kh = s_local & 1;
            int rblk = mh*4 + (g & 3) + ((g >> 2) << 3);
            const unsigned short* src = encb + (size_t)(row0 + rblk*16 + srow) * H_
                                             + t*64 + kh*32 + scol;
            char* dst = smem + (t & 1)*65536 + (rblk*2 + kh)*1024 + l*16;
            __builtin_amdgcn_global_load_lds((gbl_ptr_t)src, (lds_ptr_t)dst, 16, 0, 0);
        }
    };
    auto stageB = [&](int t, int q) {    // region q: nblk with ((nblk>>1)&1)==q
        #pragma unroll
        for (int j = 0; j < 2; ++j) {
            int s_local = j*8 + w;
            int a2 = s_local >> 2;
            int b2 = (s_local >> 1) & 1;
            int kh = s_local & 1;
            int nblk = a2*4 + q*2 + b2;
            const unsigned short* src = whb + (size_t)(col0 + nblk*16 + srow) * H_
                                            + t*64 + kh*32 + scol;
            char* dst = smem + (t & 1)*65536 + 32768 + (nblk*2 + kh)*1024 + l*16;
            __builtin_amdgcn_global_load_lds((gbl_ptr_t)src, (lds_ptr_t)dst, 16, 0, 0);
        }
    };

    f32x4  acc[8][4] = {};
    bf16x8 af[4][2];   // current mq's A fragments
    bf16x8 ba[4][2];   // whole K-tile's B fragments (held across all 4 phases)

    auto ldA = [&](int buf, int mq) {
        #pragma unroll
        for (int m2 = 0; m2 < 4; ++m2)
            #pragma unroll
            for (int kh = 0; kh < 2; ++kh) {
                int rblk = wr*8 + mq*4 + m2;
                af[m2][kh] = *reinterpret_cast<const bf16x8*>(
                    smem + buf*65536 + (rblk*2 + kh)*1024 + fr*64 + fh*16);
            }
    };
    auto ldB = [&](int buf, int nq) {
        #pragma unroll
        for (int n2 = 0; n2 < 2; ++n2)
            #pragma unroll
            for (int kh = 0; kh < 2; ++kh) {
                int nblk = wc*4 + nq*2 + n2;
                ba[nq*2 + n2][kh] = *reinterpret_cast<const bf16x8*>(
                    smem + buf*65536 + 32768 + (nblk*2 + kh)*1024 + fr*64 + fh*16);
            }
    };
    auto mfma16 = [&](int mq, int nq) {
        __builtin_amdgcn_s_setprio(1);
        #pragma unroll
        for (int kh = 0; kh < 2; ++kh)
            #pragma unroll
            for (int m2 = 0; m2 < 4; ++m2)
                #pragma unroll
                for (int n2 = 0; n2 < 2; ++n2)
                    acc[mq*4+m2][nq*2+n2] = __builtin_amdgcn_mfma_f32_16x16x32_bf16(
                        af[m2][kh], ba[nq*2+n2][kh], acc[mq*4+m2][nq*2+n2], 0, 0, 0);
        __builtin_amdgcn_s_setprio(0);
    };

    auto tile = [&](int t, bool s1, bool s2, bool last) {
        const int buf = t & 1;
        // phase 1: (mq0,nq0) -- 12 ds_reads
        ldA(buf, 0); ldB(buf, 0);
        if (s1) stageA(t+1, 1);
        __builtin_amdgcn_s_barrier();
        asm volatile("s_waitcnt lgkmcnt(0)" ::: "memory");
        mfma16(0, 0);
        __builtin_amdgcn_s_barrier();
        // phase 2: (mq0,nq1) -- 4 ds_reads, af held
        ldB(buf, 1);
        if (s2) stageA(t+2, 0);
        __builtin_amdgcn_s_barrier();
        asm volatile("s_waitcnt lgkmcnt(0)" ::: "memory");
        mfma16(0, 1);
        __builtin_amdgcn_s_barrier();
        // phase 3: (mq1,nq0) -- 8 ds_reads, ba held
        ldA(buf, 1);
        if (s2) stageB(t+2, 0);
        __builtin_amdgcn_s_barrier();
        asm volatile("s_waitcnt lgkmcnt(0)" ::: "memory");
        mfma16(1, 0);
        __builtin_amdgcn_s_barrier();
        // phase 4: (mq1,nq1) -- 0 ds_reads
        if (s2) stageB(t+2, 1);
        __builtin_amdgcn_s_barrier();
        asm volatile("s_waitcnt lgkmcnt(0)" ::: "memory");
        mfma16(1, 1);
        if (!last) asm volatile("s_waitcnt vmcnt(6)" ::: "memory");
        else       asm volatile("s_waitcnt vmcnt(0)" ::: "memory");
        __builtin_amdgcn_s_barrier();
    };

    // prologue: K0 fully + K1 minus A1[m1]; vmcnt(6) forces K0 complete
    stageA(0, 0); stageB(0, 0); stageB(0, 1); stageA(0, 1);
    stageA(1, 0); stageB(1, 0); stageB(1, 1);
    asm volatile("s_waitcnt vmcnt(6)" ::: "memory");
    __builtin_amdgcn_s_barrier();

    for (int t = 0; t < 14; ++t) tile(t, true, true, false);
    tile(14, true,  false, true);   // vmcnt(0): drain tail so K15 fully landed
    tile(15, false, false, true);

    // ---- epilogue: s_partial[row] = sum_c v[c] * tanh(qp[b][c] + x[row][c]) ----
    float vv[4], qq[4];
    #pragma unroll
    for (int n = 0; n < 4; ++n) {
        int c = col0 + wc*64 + n*16 + fr;
        vv[n] = vw[c];
        qq[n] = qp[b*H_ + c];
    }
    float* sred = (float*)smem;   // 4KB, aliases buf0 (idle; all waves past final barrier)
    #pragma unroll
    for (int m = 0; m < 8; ++m)
        #pragma unroll
        for (int r = 0; r < 4; ++r) {
            float s = 0.f;
            #pragma unroll
            for (int n = 0; n < 4; ++n)
                s += vv[n] * tanh_fast(qq[n] + acc[m][n][r]);
            s += __shfl_xor(s, 1, 64); s += __shfl_xor(s, 2, 64);
            s += __shfl_xor(s, 4, 64); s += __shfl_xor(s, 8, 64);
            if (fr == 0) sred[wc*256 + wr*128 + m*16 + fh*4 + r] = s;
        }
    __syncthreads();
    if (tid < 256) {
        float s = sred[tid] + sred[256 + tid] + sred[512 + tid] + sred[768 + tid];
        sp[(size_t)bn * M_ + row0 + tid] = s;
    }
}

// ---------------- fused scores GEMM, fp32 A in-flight (fallback, 128^2) ----------------
__global__ __launch_bounds__(256) void k_scores_f(const float* __restrict__ enc,
                                                  const unsigned short* __restrict__ whb,
                                                  const float* __restrict__ qp,
                                                  const float* __restrict__ vw,
                                                  float* __restrict__ sp) {
    __shared__ __align__(16) unsigned short As[2][128][32];
    __shared__ __align__(16) unsigned short Bs[2][128][32];
    __shared__ float sred[2][128];

    const int tid  = threadIdx.x;
    const int lane = tid & 63;
    const int wid  = tid >> 6;
    const int wr = wid >> 1, wc = wid & 1;
    const int fr = lane & 15;
    const int fk = (lane >> 4) * 8;

    const int h  = blockIdx.x;
    const int L  = (h & 7) * 1024 + (h >> 3);
    const int bm = L >> 3;
    const int bn = L & 7;
    const int row0 = bm * 128;
    const int col0 = bn * 128;
    const int b = row0 >> 12;

    const int ar = tid >> 3;
    const int ak = (tid & 7) * 4;
    const int bnr = tid >> 2;
    const int bkk = (tid & 3) * 8;

    float4 areg[4];
    auto loadA = [&](int kt) {
        #pragma unroll
        for (int p = 0; p < 4; ++p)
            areg[p] = *reinterpret_cast<const float4*>(
                &enc[(size_t)(row0 + p*32 + ar) * H_ + kt*32 + ak]);
    };
    auto writeA = [&](int buf) {
        #pragma unroll
        for (int p = 0; p < 4; ++p) {
            ushort4 u;
            u.x = f2bf(areg[p].x); u.y = f2bf(areg[p].y);
            u.z = f2bf(areg[p].z); u.w = f2bf(areg[p].w);
            *reinterpret_cast<ushort4*>(&As[buf][p*32 + ar][ak]) = u;
        }
    };
    auto stageB = [&](int buf, int kt) {
        const unsigned short* g0 = whb + (size_t)(col0 + bnr) * H_ + kt*32 + bkk;
        const unsigned short* g1 = g0 + (size_t)64 * H_;
        char* l0 = (char*)(&Bs[buf][0][0]) + tid*16;
        __builtin_amdgcn_global_load_lds((gbl_ptr_t)g0, (lds_ptr_t)l0,        16, 0, 0);
        __builtin_amdgcn_global_load_lds((gbl_ptr_t)g1, (lds_ptr_t)(l0+4096), 16, 0, 0);
    };

    f32x4 acc[4][4] = {};

    loadA(0);
    stageB(0, 0);
    writeA(0);
    __syncthreads();

    for (int kt = 0; kt < 32; ++kt) {
        const int cur = kt & 1, nxt = cur ^ 1;
        if (kt < 31) { stageB(nxt, kt + 1); loadA(kt + 1); }

        bf16x8 af[4], bfr[4];
        #pragma unroll
        for (int i = 0; i < 4; ++i) {
            af[i]  = *reinterpret_cast<const bf16x8*>(&As[cur][wr*64 + i*16 + fr][fk]);
            bfr[i] = *reinterpret_cast<const bf16x8*>(&Bs[cur][wc*64 + i*16 + fr][fk]);
        }
        #pragma unroll
        for (int i = 0; i < 4; ++i)
            #pragma unroll
            for (int j = 0; j < 4; ++j)
                acc[i][j] = __builtin_amdgcn_mfma_f32_16x16x32_bf16(af[i], bfr[j], acc[i][j], 0, 0, 0);

        if (kt < 31) writeA(nxt);
        __syncthreads();
    }

    float vv[4], qq[4];
    #pragma unroll
    for (int j = 0; j < 4; ++j) {
        int c = col0 + wc*64 + j*16 + fr;
        vv[j] = vw[c];
        qq[j] = qp[b*H_ + c];
    }
    #pragma unroll
    for (int i = 0; i < 4; ++i) {
        #pragma unroll
        for (int r = 0; r < 4; ++r) {
            float s = 0.f;
            #pragma unroll
            for (int j = 0; j < 4; ++j)
                s += vv[j] * tanh_fast(qq[j] + acc[i][j][r]);
            #pragma unroll
            for (int m = 1; m < 16; m <<= 1)
                s += __shfl_xor(s, m, 64);
            if (fr == 0)
                sred[wc][wr*64 + i*16 + (lane >> 4)*4 + r] = s;
        }
    }
    __syncthreads();
    if (tid < 128)
        sp[(size_t)bn * M_ + row0 + tid] = sred[0][tid] + sred[1][tid];
}

// ---------------- softmax over S per batch (P partial panels) ----------------
__global__ __launch_bounds__(256) void k_softmax(const float* __restrict__ sp,
                                                 float* __restrict__ attn, int P) {
    const int b = blockIdx.x, tid = threadIdx.x;
    __shared__ float red[4];
    float vals[16];
    float mx = -1e30f;
    #pragma unroll
    for (int i = 0; i < 16; ++i) {
        int s = i*256 + tid;
        float x = 0.f;
        for (int p = 0; p < P; ++p) x += sp[(size_t)p*M_ + b*S_ + s];
        vals[i] = x;
        mx = fmaxf(mx, x);
    }
    #pragma unroll
    for (int m = 1; m < 64; m <<= 1) mx = fmaxf(mx, __shfl_xor(mx, m, 64));
    if ((tid & 63) == 0) red[tid >> 6] = mx;
    __syncthreads();
    mx = fmaxf(fmaxf(red[0], red[1]), fmaxf(red[2], red[3]));
    float sum = 0.f;
    #pragma unroll
    for (int i = 0; i < 16; ++i) { vals[i] = __expf(vals[i] - mx); sum += vals[i]; }
    #pragma unroll
    for (int m = 1; m < 64; m <<= 1) sum += __shfl_xor(sum, m, 64);
    __syncthreads();
    if ((tid & 63) == 0) red[tid >> 6] = sum;
    __syncthreads();
    sum = red[0] + red[1] + red[2] + red[3];
    float inv = 1.f / sum;
    #pragma unroll
    for (int i = 0; i < 16; ++i) attn[b*S_ + i*256 + tid] = vals[i] * inv;
}

// ---------------- ctx partials, bf16 enc ----------------
__global__ __launch_bounds__(256) void k_ctx_b(const float* __restrict__ attn,
                                               const unsigned short* __restrict__ encb,
                                               float* __restrict__ ctxp) {
    const int sc = blockIdx.x;      // 0..15
    const int b  = blockIdx.y;
    const int hh = threadIdx.x * 4;
    float ax = 0.f, ay = 0.f, az = 0.f, aw = 0.f;
    const int s0 = sc * 256;
    #pragma unroll 4
    for (int s = s0; s < s0 + 256; ++s) {
        float a = attn[b*S_ + s];
        ushort4 e = *reinterpret_cast<const ushort4*>(&encb[((size_t)b*S_ + s) * H_ + hh]);
        ax += a*bf2f(e.x); ay += a*bf2f(e.y); az += a*bf2f(e.z); aw += a*bf2f(e.w);
    }
    float4 o; o.x = ax; o.y = ay; o.z = az; o.w = aw;
    *reinterpret_cast<float4*>(&ctxp[((size_t)sc*B_ + b) * H_ + hh]) = o;
}

// ---------------- ctx partials, fp32 enc (fallback) ----------------
__global__ __launch_bounds__(256) void k_ctx_f(const float* __restrict__ attn,
                                               const float* __restrict__ enc,
                                               float* __restrict__ ctxp) {
    const int sc = blockIdx.x;
    const int b  = blockIdx.y;
    const int hh = threadIdx.x * 4;
    float ax = 0.f, ay = 0.f, az = 0.f, aw = 0.f;
    const int s0 = sc * 256;
    #pragma unroll 4
    for (int s = s0; s < s0 + 256; ++s) {
        float a = attn[b*S_ + s];
        float4 e = *reinterpret_cast<const float4*>(&enc[((size_t)b*S_ + s) * H_ + hh]);
        ax += a*e.x; ay += a*e.y; az += a*e.z; aw += a*e.w;
    }
    float4 o; o.x = ax; o.y = ay; o.z = az; o.w = aw;
    *reinterpret_cast<float4*>(&ctxp[((size_t)sc*B_ + b) * H_ + hh]) = o;
}

// ---------------- out[b][o] = tanh(sum_k cat[b][k] * Wout[o][k]) ----------------
__global__ __launch_bounds__(256) void k_out(const float* __restrict__ ctxp,
                                             const float* __restrict__ q,
                                             const float* __restrict__ Wout,
                                             float* __restrict__ out) {
    const int oc = blockIdx.x, b = blockIdx.y, tid = threadIdx.x;
    __shared__ float cat[2*H_];
    for (int k = tid; k < H_; k += 256) {
        float s = 0.f;
        #pragma unroll
        for (int p = 0; p < 16; ++p) s += ctxp[((size_t)p*B_ + b) * H_ + k];
        cat[k] = s;
        cat[H_ + k] = q[b*H_ + k];
    }
    __syncthreads();
    const int o = oc*256 + tid;
    const float4* w = reinterpret_cast<const float4*>(&Wout[(size_t)o * 2*H_]);
    float acc = 0.f;
    #pragma unroll 4
    for (int k4 = 0; k4 < 2*H_/4; ++k4) {
        float4 ww = w[k4];
        acc += cat[k4*4+0]*ww.x + cat[k4*4+1]*ww.y + cat[k4*4+2]*ww.z + cat[k4*4+3]*ww.w;
    }
    out[b*H_ + o] = tanh_fast(acc);
}

extern "C" void kernel_launch(void* const* d_in, const int* in_sizes, int n_in,
                              void* d_out, int out_size, void* d_ws, size_t ws_size,
                              hipStream_t stream) {
    const float* query = (const float*)d_in[0];
    const float* enc   = (const float*)d_in[1];
    // d_in[2] = src_lengths (int64) — dead in the reference, faithfully unused
    const float* Ws    = (const float*)d_in[3];
    const float* Wh    = (const float*)d_in[4];
    const float* vw    = (const float*)d_in[5];
    const float* Wout  = (const float*)d_in[6];
    float* out = (float*)d_out;

    char* ws = (char*)d_ws;

    if (ws_size >= (266ull << 20)) {
        unsigned short* encb = (unsigned short*)ws;                        // 256 MiB
        unsigned short* whb  = (unsigned short*)(ws + (256ull << 20));     // 2 MiB
        float* sp   = (float*)(ws + (258ull << 20));                       // [4][M] 2 MiB
        float* attn = (float*)(ws + (262ull << 20));                       // 512 KiB
        float* qp   = (float*)(ws + (262ull << 20) + (512u << 10));        // 128 KiB
        float* ctxp = (float*)(ws + (263ull << 20));                       // 2 MiB

        k_cvt_enc <<<dim3(2048),    dim3(256), 0, stream>>>(enc, encb, M_*H_/8);
        k_cvt_bf16<<<dim3(1024),    dim3(256), 0, stream>>>(Wh, whb, H_*H_/4);
        k_qproj   <<<dim3(4, 32),   dim3(256), 0, stream>>>(query, Ws, qp);
        k_scores8 <<<dim3(2048),    dim3(512), 0, stream>>>(encb, whb, qp, vw, sp);
        k_softmax <<<dim3(32),      dim3(256), 0, stream>>>(sp, attn, 4);
        k_ctx_b   <<<dim3(16, 32),  dim3(256), 0, stream>>>(attn, encb, ctxp);
        k_out     <<<dim3(4, 32),   dim3(256), 0, stream>>>(ctxp, query, Wout, out);
    } else {
        unsigned short* whb = (unsigned short*)ws;
        float* sp   = (float*)(ws + (2u  << 20));
        float* attn = (float*)(ws + (6u  << 20));
        float* qp   = (float*)(ws + (6u  << 20) + (512u << 10));
        float* ctxp = (float*)(ws + (7u  << 20));

        k_cvt_bf16<<<dim3(1024),    dim3(256), 0, stream>>>(Wh, whb, H_*H_/4);
        k_qproj   <<<dim3(4, 32),   dim3(256), 0, stream>>>(query, Ws, qp);
        k_scores_f<<<dim3(8192),    dim3(256), 0, stream>>>(enc, whb, qp, vw, sp);
        k_softmax <<<dim3(32),      dim3(256), 0, stream>>>(sp, attn, 8);
        k_ctx_f   <<<dim3(16, 32),  dim3(256), 0, stream>>>(attn, enc, ctxp);
        k_out     <<<dim3(4, 32),   dim3(256), 0, stream>>>(ctxp, query, Wout, out);
    }
}